// Round 6
// baseline (101.092 us; speedup 1.0000x reference)
//
#include <hip/hip_runtime.h>
#include <hip/hip_bf16.h>
#include <math.h>

#define TB 256
#define TILES 4
#define PI_F 3.14159265358979323846f

typedef __attribute__((ext_vector_type(8))) short short8;
typedef __attribute__((ext_vector_type(4))) float f32x4;

union Frag { short8 v; ushort u[8]; uint w[4]; };

__device__ __forceinline__ uint pk2(float a, float b) {
    union { __hip_bfloat162 h; uint u; } cv;
    cv.h = __float22bfloat162_rn(make_float2(a, b));   // packed RNE cvt
    return cv.u;
}

// fp32x8 -> bf16 hi frag + bf16 residual(lo) frag
__device__ __forceinline__ void cvt8(const float4& p0, const float4& p1, Frag& hi, Frag& lo) {
    float f[8] = {p0.x, p0.y, p0.z, p0.w, p1.x, p1.y, p1.z, p1.w};
    #pragma unroll
    for (int e = 0; e < 4; ++e) hi.w[e] = pk2(f[2 * e], f[2 * e + 1]);
    #pragma unroll
    for (int e = 0; e < 4; ++e) {
        float r0 = f[2 * e]     - __uint_as_float(hi.w[e] << 16);
        float r1 = f[2 * e + 1] - __uint_as_float(hi.w[e] & 0xffff0000u);
        lo.w[e] = pk2(r0, r1);
    }
}

__device__ __forceinline__ float fast_tanh(float p) {
    float t = __expf(2.0f * p);
    return 1.0f - __fdividef(2.0f, t + 1.0f);
}

__global__ __launch_bounds__(TB, 2) void sqru_fused_kernel(
    const float* __restrict__ x, const float* __restrict__ Wp,
    const float* __restrict__ bp, const float* __restrict__ qw,
    const float* __restrict__ W1, const float* __restrict__ b1,
    const float* __restrict__ W2, const float* __restrict__ b2,
    float* __restrict__ out, int nrows)
{
    __shared__ ushort whi[512 * 8];        // 8 KB Wp hi frags: [(s*4+kbi)*16+jc]
    __shared__ ushort wlo[512 * 8];        // 8 KB Wp lo frags
    __shared__ float  proj_s[4][16 * 17];
    __shared__ float  qbuf[4][16][8];
    __shared__ float  w1_s[32 * 8];
    __shared__ float  w2_s[10 * 32];
    __shared__ float  b1_s[32];
    __shared__ float  b2_s[10];
    __shared__ float  rot_s[8][3][6];

    const int t   = threadIdx.x;
    const int w   = t >> 6;
    const int l   = t & 63;
    const int jc  = l & 15;
    const int kbi = l >> 4;
    const int gw  = blockIdx.x * 4 + w;          // global wave id
    const int tile0 = gw * TILES;

    // ---- issue tile0's x loads FIRST (in flight during Wp staging) ----
    int r0 = tile0 * 16 + jc;
    if (r0 >= nrows) r0 = nrows - 1;
    const float* xp = x + (size_t)r0 * 256 + kbi * 8;
    float4 xb[8][2];
    #pragma unroll
    for (int s = 0; s < 8; ++s) {
        xb[s][0] = *(const float4*)(xp + s * 32);
        xb[s][1] = *(const float4*)(xp + s * 32 + 4);
    }

    // ---- one-time staging: Wp -> bf16 hi/lo frags, head weights, rot table ----
    if (t < 64) ((float4*)w1_s)[t] = ((const float4*)W1)[t];
    if (t < 80) ((float4*)w2_s)[t] = ((const float4*)W2)[t];
    if (t < 32) b1_s[t] = b1[t];
    if (t < 10) b2_s[t] = b2[t];
    if (t < 24) {
        int u = t / 3, l2 = t % 3;
        float q0 = qw[u * 9 + l2 * 3 + 0];
        float q1 = qw[u * 9 + l2 * 3 + 1];
        float q2 = qw[u * 9 + l2 * 3 + 2];
        rot_s[u][l2][0] = cosf(q0);        rot_s[u][l2][1] = sinf(q0);
        rot_s[u][l2][2] = cosf(0.5f * q1); rot_s[u][l2][3] = sinf(0.5f * q1);
        rot_s[u][l2][4] = cosf(q2);        rot_s[u][l2][5] = sinf(q2);
    }
    #pragma unroll
    for (int ff = 0; ff < 2; ++ff) {
        int f = t + ff * 256;
        int jc2 = f & 15, kb2 = (f >> 4) & 3, s2 = f >> 6;
        const float* wp = Wp + jc2 * 256 + s2 * 32 + kb2 * 8;
        float4 p0 = *(const float4*)wp;
        float4 p1 = *(const float4*)(wp + 4);
        Frag h, lo2;
        cvt8(p0, p1, h, lo2);
        ((short8*)whi)[f] = h.v;
        ((short8*)wlo)[f] = lo2.v;
    }
    __syncthreads();   // only barrier in the kernel

    const float bpj  = bp[jc];
    const int   srow = l >> 2;
    const int   s4   = l & 3;
    const short8* whi_f = (const short8*)whi;
    const short8* wlo_f = (const short8*)wlo;

    for (int tt = 0; tt < TILES; ++tt) {
        const int tile = tile0 + tt;
        const bool pf  = (tt < TILES - 1);
        int rn = (tile + 1) * 16 + jc;
        if (rn >= nrows) rn = nrows - 1;
        const float* xpn = x + (size_t)rn * 256 + kbi * 8;

        f32x4 accm = {bpj, bpj, bpj, bpj};
        f32x4 accc = {0.0f, 0.0f, 0.0f, 0.0f};

        // ---- MFMA GEMV: 8 K-steps; reissue xb[s] for next tile after use ----
        #pragma unroll
        for (int s = 0; s < 8; ++s) {
            Frag bh, bl, ah, al;
            bh.v = whi_f[(s * 4 + kbi) * 16 + jc];
            bl.v = wlo_f[(s * 4 + kbi) * 16 + jc];
            cvt8(xb[s][0], xb[s][1], ah, al);
            if (pf) {
                xb[s][0] = *(const float4*)(xpn + s * 32);
                xb[s][1] = *(const float4*)(xpn + s * 32 + 4);
            }
            accm = __builtin_amdgcn_mfma_f32_16x16x32_bf16(ah.v, bh.v, accm, 0, 0, 0);
            accc = __builtin_amdgcn_mfma_f32_16x16x32_bf16(al.v, bh.v, accc, 0, 0, 0);
            accc = __builtin_amdgcn_mfma_f32_16x16x32_bf16(ah.v, bl.v, accc, 0, 0, 0);
        }

        // ---- intra-wave transpose: C[row=kbi*4+r][col=jc] ----
        #pragma unroll
        for (int r = 0; r < 4; ++r)
            proj_s[w][(kbi * 4 + r) * 17 + jc] = accm[r] + accc[r];

        // ---- unit-split circuit: 4 lanes/row, 2 units each ----
        float4 pv = *(const float4*)&proj_s[w][srow * 17 + s4 * 4];

        float qv[2];
        #pragma unroll
        for (int uu = 0; uu < 2; ++uu) {
            const int u = 2 * s4 + uu;
            float p0 = (uu == 0) ? pv.x : pv.z;
            float p1 = (uu == 0) ? pv.y : pv.w;
            float th0 = fast_tanh(p0);
            float th1 = fast_tanh(p1);
            float c  = __cosf(0.5f * PI_F * th0);
            float s  = __sinf(0.5f * PI_F * th0);
            float zr = __cosf(PI_F * th1);
            float zi = __sinf(PI_F * th1);

            float ar = c, ai = 0.0f, br = s, bi = 0.0f;
            #pragma unroll
            for (int l2 = 0; l2 < 3; ++l2) {
                if (l2 > 0) {
                    float nar = c * ar - s * br, nai = c * ai - s * bi;
                    float nbr = s * ar + c * br, nbi = s * ai + c * bi;
                    ar = nar; ai = nai; br = nbr; bi = nbi;
                }
                float e0r = rot_s[u][l2][0], e0i = rot_s[u][l2][1];
                float p2r = zr * e0r - zi * e0i;
                float p2q = zr * e0i + zi * e0r;
                float nbr = br * p2r - bi * p2q, nbi = br * p2q + bi * p2r;
                br = nbr; bi = nbi;
                float c1 = rot_s[u][l2][2], s1 = rot_s[u][l2][3];
                float tar = c1 * ar - s1 * br, tai = c1 * ai - s1 * bi;
                float tbr = s1 * ar + c1 * br, tbi = s1 * ai + c1 * bi;
                ar = tar; ai = tai; br = tbr; bi = tbi;
                if (l2 < 2) {
                    float e2r = rot_s[u][l2][4], e2i = rot_s[u][l2][5];
                    float ubr = br * e2r - bi * e2i, ubi = br * e2i + bi * e2r;
                    br = ubr; bi = ubi;
                }
            }
            qv[uu] = (ar * ar + ai * ai) - (br * br + bi * bi);
        }

        *(float2*)&qbuf[w][srow][2 * s4] = make_float2(qv[0], qv[1]);
        float4 qa = *(const float4*)&qbuf[w][srow][0];
        float4 qb = *(const float4*)&qbuf[w][srow][4];

        // ---- head: lane covers j = s4*8..s4*8+7, 4-lane reduce ----
        float ov[10];
        #pragma unroll
        for (int c2 = 0; c2 < 10; ++c2) ov[c2] = 0.0f;
        #pragma unroll
        for (int jj = 0; jj < 8; ++jj) {
            const int j = s4 * 8 + jj;
            float h = b1_s[j];
            h = fmaf(qa.x, w1_s[j * 8 + 0], h);
            h = fmaf(qa.y, w1_s[j * 8 + 1], h);
            h = fmaf(qa.z, w1_s[j * 8 + 2], h);
            h = fmaf(qa.w, w1_s[j * 8 + 3], h);
            h = fmaf(qb.x, w1_s[j * 8 + 4], h);
            h = fmaf(qb.y, w1_s[j * 8 + 5], h);
            h = fmaf(qb.z, w1_s[j * 8 + 6], h);
            h = fmaf(qb.w, w1_s[j * 8 + 7], h);
            h = fmaxf(h, 0.0f);
            #pragma unroll
            for (int c2 = 0; c2 < 10; ++c2) ov[c2] = fmaf(h, w2_s[c2 * 32 + j], ov[c2]);
        }
        #pragma unroll
        for (int c2 = 0; c2 < 10; ++c2) {
            ov[c2] += __shfl_xor(ov[c2], 1);
            ov[c2] += __shfl_xor(ov[c2], 2);
            ov[c2] += b2_s[c2];
        }

        const int orow = tile * 16 + srow;
        if (orow < nrows) {
            float2* op = (float2*)(out + (size_t)orow * 10);
            float lo = (s4 == 0) ? ov[0] : (s4 == 1) ? ov[2] : (s4 == 2) ? ov[4] : ov[6];
            float hi = (s4 == 0) ? ov[1] : (s4 == 1) ? ov[3] : (s4 == 2) ? ov[5] : ov[7];
            op[s4] = make_float2(lo, hi);
            if (s4 == 0) op[4] = make_float2(ov[8], ov[9]);
        }
    }
}

extern "C" void kernel_launch(void* const* d_in, const int* in_sizes, int n_in,
                              void* d_out, int out_size, void* d_ws, size_t ws_size,
                              hipStream_t stream) {
    const float* x  = (const float*)d_in[0];
    const float* Wp = (const float*)d_in[1];
    const float* bp = (const float*)d_in[2];
    const float* qw = (const float*)d_in[3];
    const float* W1 = (const float*)d_in[4];
    const float* b1 = (const float*)d_in[5];
    const float* W2 = (const float*)d_in[6];
    const float* b2 = (const float*)d_in[7];
    float* out = (float*)d_out;

    const int nrows = in_sizes[0] / 256;
    const int rows_per_block = 16 * 4 * TILES;   // 4 waves x TILES tiles x 16 rows
    const int nblocks = (nrows + rows_per_block - 1) / rows_per_block;
    sqru_fused_kernel<<<nblocks, TB, 0, stream>>>(x, Wp, bp, qw, W1, b1, W2, b2, out, nrows);
}

// Round 7
// 56.434 us; speedup vs baseline: 1.7914x; 1.7914x over previous
//
#include <hip/hip_runtime.h>
#include <hip/hip_bf16.h>
#include <math.h>

#define TB 256
#define TILES_PER_WAVE 4
#define PI_F 3.14159265358979323846f

// dynamic smem partition (floats)
#define XOFF   0            // 4 waves x 2 halves x 4096 floats = 32768 (128 KB)
#define POFF   32768        // proj: 4 x 16*17 = 1088
#define QOFF   33856        // qbuf: 4 x 16 x 8 = 512
#define W1OFF  34368        // 256
#define W2OFF  34624        // 320
#define B1OFF  34944        // 32
#define B2OFF  34976        // 16
#define ROTOFF 34992        // 144
#define SMEM_FLOATS 35136
#define SMEM_BYTES  (SMEM_FLOATS * 4)

#define WAITVM(n) asm volatile("s_waitcnt vmcnt(" #n ")" ::: "memory")

typedef __attribute__((address_space(1))) const void GlobalVoid;
typedef __attribute__((address_space(3))) void LdsVoid;

typedef __attribute__((ext_vector_type(8))) short short8;
typedef __attribute__((ext_vector_type(4))) float f32x4;

union Frag { short8 v; ushort u[8]; uint w[4]; };

__device__ __forceinline__ uint pk2(float a, float b) {
    union { __hip_bfloat162 h; uint u; } cv;
    cv.h = __float22bfloat162_rn(make_float2(a, b));
    return cv.u;
}
__device__ __forceinline__ void cvt8(const float4& p0, const float4& p1, Frag& hi, Frag& lo) {
    float f[8] = {p0.x, p0.y, p0.z, p0.w, p1.x, p1.y, p1.z, p1.w};
    #pragma unroll
    for (int e = 0; e < 4; ++e) hi.w[e] = pk2(f[2 * e], f[2 * e + 1]);
    #pragma unroll
    for (int e = 0; e < 4; ++e) {
        float r0 = f[2 * e]     - __uint_as_float(hi.w[e] << 16);
        float r1 = f[2 * e + 1] - __uint_as_float(hi.w[e] & 0xffff0000u);
        lo.w[e] = pk2(r0, r1);
    }
}
__device__ __forceinline__ float fast_tanh(float p) {
    float t = __expf(2.0f * p);
    return 1.0f - __fdividef(2.0f, t + 1.0f);
}

__global__ __launch_bounds__(TB, 2) void sqru_fused_kernel(
    const float* __restrict__ x, const float* __restrict__ Wp,
    const float* __restrict__ bp, const float* __restrict__ qw,
    const float* __restrict__ W1, const float* __restrict__ b1,
    const float* __restrict__ W2, const float* __restrict__ b2,
    float* __restrict__ out, int nrows)
{
    extern __shared__ float smem[];

    const int t   = threadIdx.x;
    const int w   = t >> 6;
    const int l   = t & 63;
    const int jc  = l & 15;     // MFMA M-row / proj col
    const int kbi = l >> 4;     // K sub-group

    // ---- small weights -> LDS ----
    if (t < 64) ((float4*)(smem + W1OFF))[t] = ((const float4*)W1)[t];
    if (t < 80) ((float4*)(smem + W2OFF))[t] = ((const float4*)W2)[t];
    if (t < 32) smem[B1OFF + t] = b1[t];
    if (t < 10) smem[B2OFF + t] = b2[t];
    if (t < 24) {
        int u = t / 3, l2 = t % 3;
        float q0 = qw[u * 9 + l2 * 3 + 0];
        float q1 = qw[u * 9 + l2 * 3 + 1];
        float q2 = qw[u * 9 + l2 * 3 + 2];
        float* rr = smem + ROTOFF + (u * 3 + l2) * 6;
        rr[0] = cosf(q0);        rr[1] = sinf(q0);
        rr[2] = cosf(0.5f * q1); rr[3] = sinf(0.5f * q1);
        rr[4] = cosf(q2);        rr[5] = sinf(q2);
    }
    __syncthreads();   // only barrier in the kernel

    // ---- Wp -> per-lane bf16 hi/lo fragments in REGISTERS (reused all tiles) ----
    Frag whi_r[8], wlo_r[8];
    {
        const float* wpb = Wp + jc * 256 + kbi * 8;
        #pragma unroll
        for (int s = 0; s < 8; ++s) {
            float4 w0 = *(const float4*)(wpb + s * 32);
            float4 w1v = *(const float4*)(wpb + s * 32 + 4);
            cvt8(w0, w1v, whi_r[s], wlo_r[s]);
        }
    }
    const float bpj = bp[jc];

    const int gw = blockIdx.x * 4 + w;            // global wave id
    const int t0 = gw * TILES_PER_WAVE;           // first tile (16 rows each)
    float* xwave = smem + XOFF + w * 8192;

    // swizzled ds-read float offsets (chunk = 16B): pos = (s*8 + kbi*2+k) ^ (jc&7)
    const int g  = jc & 7;
    const int e0 = (((kbi * 2) ^ g) << 2);        // float offset within row slab
    const int e1 = (((kbi * 2 + 1) ^ g) << 2);

    // ---- per-wave DMA stage: 16 rows x 1KB, linear dest, pre-swizzled src ----
    auto stage = [&](int half, int tile) {
        float* dstbase = xwave + half * 4096;
        #pragma unroll
        for (int i = 0; i < 16; ++i) {
            int r = tile * 16 + i;
            r = (r < nrows) ? r : (nrows - 1);
            const float* src = x + (size_t)r * 256 + ((l ^ (i & 7)) << 2);
            __builtin_amdgcn_global_load_lds((GlobalVoid*)src,
                                             (LdsVoid*)(dstbase + i * 256), 16, 0, 0);
        }
    };

    stage(0, t0 + 0);
    stage(1, t0 + 1);

    const int srow = l >> 2;
    const int s4   = l & 3;
    const float* w1_s = smem + W1OFF;
    const float* w2_s = smem + W2OFF;
    const float* b1_s = smem + B1OFF;
    const float* b2_s = smem + B2OFF;

    for (int it = 0; it < TILES_PER_WAVE; ++it) {
        if (it < TILES_PER_WAVE - 1) { WAITVM(16); } else { WAITVM(0); }

        const int half = it & 1;
        const int tile = t0 + it;
        const float* xrow = xwave + half * 4096 + jc * 256;

        f32x4 accm = {bpj, bpj, bpj, bpj};
        f32x4 accc = {0.0f, 0.0f, 0.0f, 0.0f};

        #pragma unroll
        for (int s = 0; s < 8; ++s) {
            float4 xv0 = *(const float4*)(xrow + s * 32 + e0);
            float4 xv1 = *(const float4*)(xrow + s * 32 + e1);
            Frag ah, al;
            cvt8(xv0, xv1, ah, al);
            accm = __builtin_amdgcn_mfma_f32_16x16x32_bf16(ah.v, whi_r[s].v, accm, 0, 0, 0);
            accc = __builtin_amdgcn_mfma_f32_16x16x32_bf16(al.v, whi_r[s].v, accc, 0, 0, 0);
            accc = __builtin_amdgcn_mfma_f32_16x16x32_bf16(ah.v, wlo_r[s].v, accc, 0, 0, 0);
        }

        // ---- transpose C[row=kbi*4+r][col=jc] via wave-private LDS ----
        float* pj = smem + POFF + w * 272;
        #pragma unroll
        for (int r = 0; r < 4; ++r)
            pj[(kbi * 4 + r) * 17 + jc] = accm[r] + accc[r];

        float4 pv = *(const float4*)(pj + srow * 17 + s4 * 4);

        // ---- unit-split circuit: 4 lanes/row, 2 units each ----
        float qv[2];
        #pragma unroll
        for (int uu = 0; uu < 2; ++uu) {
            const int u = 2 * s4 + uu;
            float p0 = (uu == 0) ? pv.x : pv.z;
            float p1 = (uu == 0) ? pv.y : pv.w;
            float th0 = fast_tanh(p0);
            float th1 = fast_tanh(p1);
            float c  = __cosf(0.5f * PI_F * th0);
            float s  = __sinf(0.5f * PI_F * th0);
            float zr = __cosf(PI_F * th1);
            float zi = __sinf(PI_F * th1);

            float ar = c, ai = 0.0f, br = s, bi = 0.0f;
            #pragma unroll
            for (int l2 = 0; l2 < 3; ++l2) {
                if (l2 > 0) {
                    float nar = c * ar - s * br, nai = c * ai - s * bi;
                    float nbr = s * ar + c * br, nbi = s * ai + c * bi;
                    ar = nar; ai = nai; br = nbr; bi = nbi;
                }
                const float* rr = smem + ROTOFF + (u * 3 + l2) * 6;
                float p2r = zr * rr[0] - zi * rr[1];
                float p2q = zr * rr[1] + zi * rr[0];
                float nbr = br * p2r - bi * p2q, nbi = br * p2q + bi * p2r;
                br = nbr; bi = nbi;
                float c1 = rr[2], s1 = rr[3];
                float tar = c1 * ar - s1 * br, tai = c1 * ai - s1 * bi;
                float tbr = s1 * ar + c1 * br, tbi = s1 * ai + c1 * bi;
                ar = tar; ai = tai; br = tbr; bi = tbi;
                if (l2 < 2) {
                    float ubr = br * rr[4] - bi * rr[5], ubi = br * rr[5] + bi * rr[4];
                    br = ubr; bi = ubi;
                }
            }
            qv[uu] = (ar * ar + ai * ai) - (br * br + bi * bi);
        }

        float* qb = smem + QOFF + w * 128 + srow * 8;
        *(float2*)(qb + 2 * s4) = make_float2(qv[0], qv[1]);
        float4 qa = *(const float4*)(qb + 0);
        float4 qbv = *(const float4*)(qb + 4);

        // ---- head: lane covers j = s4*8..s4*8+7, 4-lane reduce ----
        float ov[10];
        #pragma unroll
        for (int c2 = 0; c2 < 10; ++c2) ov[c2] = 0.0f;
        #pragma unroll
        for (int jj = 0; jj < 8; ++jj) {
            const int j = s4 * 8 + jj;
            float h = b1_s[j];
            h = fmaf(qa.x,  w1_s[j * 8 + 0], h);
            h = fmaf(qa.y,  w1_s[j * 8 + 1], h);
            h = fmaf(qa.z,  w1_s[j * 8 + 2], h);
            h = fmaf(qa.w,  w1_s[j * 8 + 3], h);
            h = fmaf(qbv.x, w1_s[j * 8 + 4], h);
            h = fmaf(qbv.y, w1_s[j * 8 + 5], h);
            h = fmaf(qbv.z, w1_s[j * 8 + 6], h);
            h = fmaf(qbv.w, w1_s[j * 8 + 7], h);
            h = fmaxf(h, 0.0f);
            #pragma unroll
            for (int c2 = 0; c2 < 10; ++c2) ov[c2] = fmaf(h, w2_s[c2 * 32 + j], ov[c2]);
        }
        #pragma unroll
        for (int c2 = 0; c2 < 10; ++c2) {
            ov[c2] += __shfl_xor(ov[c2], 1);
            ov[c2] += __shfl_xor(ov[c2], 2);
            ov[c2] += b2_s[c2];
        }

        const int orow = tile * 16 + srow;
        if (orow < nrows) {
            float2* op = (float2*)(out + (size_t)orow * 10);
            float lo = (s4 == 0) ? ov[0] : (s4 == 1) ? ov[2] : (s4 == 2) ? ov[4] : ov[6];
            float hi = (s4 == 0) ? ov[1] : (s4 == 1) ? ov[3] : (s4 == 2) ? ov[5] : ov[7];
            op[s4] = make_float2(lo, hi);
            if (s4 == 0) op[4] = make_float2(ov[8], ov[9]);
        }

        // prefetch tile it+2 into the half we just consumed
        if (it < TILES_PER_WAVE - 2) stage(half, tile + 2);
    }
}

extern "C" void kernel_launch(void* const* d_in, const int* in_sizes, int n_in,
                              void* d_out, int out_size, void* d_ws, size_t ws_size,
                              hipStream_t stream) {
    const float* x  = (const float*)d_in[0];
    const float* Wp = (const float*)d_in[1];
    const float* bp = (const float*)d_in[2];
    const float* qw = (const float*)d_in[3];
    const float* W1 = (const float*)d_in[4];
    const float* b1 = (const float*)d_in[5];
    const float* W2 = (const float*)d_in[6];
    const float* b2 = (const float*)d_in[7];
    float* out = (float*)d_out;

    const int nrows = in_sizes[0] / 256;
    const int rows_per_block = 16 * TILES_PER_WAVE * 4;   // 256
    const int nblocks = (nrows + rows_per_block - 1) / rows_per_block;

    static int smem_set = 0;
    (void)smem_set;
    hipFuncSetAttribute((const void*)sqru_fused_kernel,
                        hipFuncAttributeMaxDynamicSharedMemorySize, SMEM_BYTES);

    sqru_fused_kernel<<<nblocks, TB, SMEM_BYTES, stream>>>(
        x, Wp, bp, qw, W1, b1, W2, b2, out, nrows);
}

// Round 8
// 32.566 us; speedup vs baseline: 3.1042x; 1.7329x over previous
//
#include <hip/hip_runtime.h>
#include <hip/hip_bf16.h>
#include <math.h>

#define TB 256
#define TILES 2
#define PI_F 3.14159265358979323846f

typedef __attribute__((ext_vector_type(8))) short short8;
typedef __attribute__((ext_vector_type(4))) float f32x4;

union Frag { short8 v; ushort u[8]; uint w[4]; };

__device__ __forceinline__ uint pk2(float a, float b) {
    union { __hip_bfloat162 h; uint u; } cv;
    cv.h = __float22bfloat162_rn(make_float2(a, b));   // packed RNE cvt
    return cv.u;
}

// x path: hi-only bf16 (cheap: 4 packed cvts per 8 floats)
__device__ __forceinline__ void cvt_hi(const float4& p0, const float4& p1, Frag& hi) {
    hi.w[0] = pk2(p0.x, p0.y); hi.w[1] = pk2(p0.z, p0.w);
    hi.w[2] = pk2(p1.x, p1.y); hi.w[3] = pk2(p1.z, p1.w);
}

// Wp path (one-time): hi + residual lo
__device__ __forceinline__ void cvt8(const float4& p0, const float4& p1, Frag& hi, Frag& lo) {
    float f[8] = {p0.x, p0.y, p0.z, p0.w, p1.x, p1.y, p1.z, p1.w};
    #pragma unroll
    for (int e = 0; e < 4; ++e) hi.w[e] = pk2(f[2 * e], f[2 * e + 1]);
    #pragma unroll
    for (int e = 0; e < 4; ++e) {
        float r0 = f[2 * e]     - __uint_as_float(hi.w[e] << 16);
        float r1 = f[2 * e + 1] - __uint_as_float(hi.w[e] & 0xffff0000u);
        lo.w[e] = pk2(r0, r1);
    }
}

__device__ __forceinline__ float fast_tanh(float p) {
    float t = __expf(2.0f * p);
    return 1.0f - __fdividef(2.0f, t + 1.0f);
}

__global__ __launch_bounds__(TB, 4) void sqru_fused_kernel(
    const float* __restrict__ x, const float* __restrict__ Wp,
    const float* __restrict__ bp, const float* __restrict__ qw,
    const float* __restrict__ W1, const float* __restrict__ b1,
    const float* __restrict__ W2, const float* __restrict__ b2,
    float* __restrict__ out, int nrows)
{
    __shared__ ushort whi[512 * 8];        // 8 KB Wp hi frags [(s*4+kbi)*16+jc]
    __shared__ ushort wlo[512 * 8];        // 8 KB Wp lo frags
    __shared__ float  proj_s[4][16 * 17];  // wave-private transpose
    __shared__ float  qbuf[4][16][8];
    __shared__ float  w1_s[32 * 8];
    __shared__ float  w2_s[10 * 32];
    __shared__ float  b1_s[32];
    __shared__ float  b2_s[10];
    __shared__ float  rot_s[8][3][6];

    const int t   = threadIdx.x;
    const int w   = t >> 6;
    const int l   = t & 63;
    const int jc  = l & 15;     // M-row (x batch row) and N-col (proj out) index
    const int kbi = l >> 4;     // K sub-group
    const int gw  = blockIdx.x * 4 + w;
    const int tile0 = gw * TILES;

    int r0 = tile0 * 16 + jc;       if (r0 >= nrows) r0 = nrows - 1;
    int r1 = (tile0 + 1) * 16 + jc; if (r1 >= nrows) r1 = nrows - 1;
    const float* xp0 = x + (size_t)r0 * 256 + kbi * 8;
    const float* xp1 = x + (size_t)r1 * 256 + kbi * 8;

    // ---- ring prologue: tile0 K-steps 0..3 in flight before weight staging ----
    float4 xa0 = *(const float4*)(xp0 +   0), xb0 = *(const float4*)(xp0 +   4);
    float4 xa1 = *(const float4*)(xp0 +  32), xb1 = *(const float4*)(xp0 +  36);
    float4 xa2 = *(const float4*)(xp0 +  64), xb2 = *(const float4*)(xp0 +  68);
    float4 xa3 = *(const float4*)(xp0 +  96), xb3 = *(const float4*)(xp0 + 100);

    // ---- one-time weight staging ----
    if (t < 64) ((float4*)w1_s)[t] = ((const float4*)W1)[t];
    if (t < 80) ((float4*)w2_s)[t] = ((const float4*)W2)[t];
    if (t < 32) b1_s[t] = b1[t];
    if (t < 10) b2_s[t] = b2[t];
    if (t < 24) {
        int u = t / 3, l2 = t % 3;
        float q0 = qw[u * 9 + l2 * 3 + 0];
        float q1 = qw[u * 9 + l2 * 3 + 1];
        float q2 = qw[u * 9 + l2 * 3 + 2];
        rot_s[u][l2][0] = cosf(q0);        rot_s[u][l2][1] = sinf(q0);
        rot_s[u][l2][2] = cosf(0.5f * q1); rot_s[u][l2][3] = sinf(0.5f * q1);
        rot_s[u][l2][4] = cosf(q2);        rot_s[u][l2][5] = sinf(q2);
    }
    #pragma unroll
    for (int ff = 0; ff < 2; ++ff) {
        int f = t + ff * 256;
        int jc2 = f & 15, kb2 = (f >> 4) & 3, s2 = f >> 6;
        const float* wp = Wp + jc2 * 256 + s2 * 32 + kb2 * 8;
        float4 p0 = *(const float4*)wp;
        float4 p1 = *(const float4*)(wp + 4);
        Frag h, lo2;
        cvt8(p0, p1, h, lo2);
        ((short8*)whi)[f] = h.v;
        ((short8*)wlo)[f] = lo2.v;
    }
    __syncthreads();   // only barrier in the kernel

    const float bpj  = bp[jc];
    const int   srow = l >> 2;
    const int   s4   = l & 3;
    const short8* whi_f = (const short8*)whi;
    const short8* wlo_f = (const short8*)wlo;

    auto do_tile = [&](const float* xpc, const float* xpn, int tile) {
        f32x4 accm = {bpj, bpj, bpj, bpj};
        f32x4 accc = {0.0f, 0.0f, 0.0f, 0.0f};

        // 8 static K-steps; slots refilled 4 ahead, crossing into next tile
        #define STEP(S, XA, XB, PF, PS)                                            \
        {                                                                          \
            Frag ah; cvt_hi(XA, XB, ah);                                           \
            XA = *(const float4*)((PF) + (PS) * 32);                               \
            XB = *(const float4*)((PF) + (PS) * 32 + 4);                           \
            Frag bh, bl;                                                           \
            bh.v = whi_f[((S) * 4 + kbi) * 16 + jc];                               \
            bl.v = wlo_f[((S) * 4 + kbi) * 16 + jc];                               \
            accm = __builtin_amdgcn_mfma_f32_16x16x32_bf16(ah.v, bh.v, accm, 0, 0, 0); \
            accc = __builtin_amdgcn_mfma_f32_16x16x32_bf16(ah.v, bl.v, accc, 0, 0, 0); \
        }
        STEP(0, xa0, xb0, xpc, 4)
        STEP(1, xa1, xb1, xpc, 5)
        STEP(2, xa2, xb2, xpc, 6)
        STEP(3, xa3, xb3, xpc, 7)
        STEP(4, xa0, xb0, xpn, 0)
        STEP(5, xa1, xb1, xpn, 1)
        STEP(6, xa2, xb2, xpn, 2)
        STEP(7, xa3, xb3, xpn, 3)
        #undef STEP

        // ---- transpose C[row=kbi*4+r][col=jc] via wave-private LDS ----
        #pragma unroll
        for (int r = 0; r < 4; ++r)
            proj_s[w][(kbi * 4 + r) * 17 + jc] = accm[r] + accc[r];

        float4 pv = *(const float4*)&proj_s[w][srow * 17 + s4 * 4];

        // ---- unit-split circuit: 4 lanes/row, 2 units each ----
        float qv[2];
        #pragma unroll
        for (int uu = 0; uu < 2; ++uu) {
            const int u = 2 * s4 + uu;
            float p0 = (uu == 0) ? pv.x : pv.z;
            float p1 = (uu == 0) ? pv.y : pv.w;
            float th0 = fast_tanh(p0);
            float th1 = fast_tanh(p1);
            float c  = __cosf(0.5f * PI_F * th0);
            float s  = __sinf(0.5f * PI_F * th0);
            float zr = __cosf(PI_F * th1);
            float zi = __sinf(PI_F * th1);

            float ar = c, ai = 0.0f, br = s, bi = 0.0f;
            #pragma unroll
            for (int l2 = 0; l2 < 3; ++l2) {
                if (l2 > 0) {
                    float nar = c * ar - s * br, nai = c * ai - s * bi;
                    float nbr = s * ar + c * br, nbi = s * ai + c * bi;
                    ar = nar; ai = nai; br = nbr; bi = nbi;
                }
                float e0r = rot_s[u][l2][0], e0i = rot_s[u][l2][1];
                float p2r = zr * e0r - zi * e0i;
                float p2q = zr * e0i + zi * e0r;
                float nbr = br * p2r - bi * p2q, nbi = br * p2q + bi * p2r;
                br = nbr; bi = nbi;
                float c1 = rot_s[u][l2][2], s1 = rot_s[u][l2][3];
                float tar = c1 * ar - s1 * br, tai = c1 * ai - s1 * bi;
                float tbr = s1 * ar + c1 * br, tbi = s1 * ai + c1 * bi;
                ar = tar; ai = tai; br = tbr; bi = tbi;
                if (l2 < 2) {
                    float e2r = rot_s[u][l2][4], e2i = rot_s[u][l2][5];
                    float ubr = br * e2r - bi * e2i, ubi = br * e2i + bi * e2r;
                    br = ubr; bi = ubi;
                }
            }
            qv[uu] = (ar * ar + ai * ai) - (br * br + bi * bi);
        }

        float* qb = &qbuf[w][srow][0];
        *(float2*)(qb + 2 * s4) = make_float2(qv[0], qv[1]);
        float4 qa  = *(const float4*)(qb + 0);
        float4 qbv = *(const float4*)(qb + 4);

        // ---- head: lane covers j = s4*8..s4*8+7, 4-lane reduce ----
        float ov[10];
        #pragma unroll
        for (int c2 = 0; c2 < 10; ++c2) ov[c2] = 0.0f;
        #pragma unroll
        for (int jj = 0; jj < 8; ++jj) {
            const int j = s4 * 8 + jj;
            float h = b1_s[j];
            h = fmaf(qa.x,  w1_s[j * 8 + 0], h);
            h = fmaf(qa.y,  w1_s[j * 8 + 1], h);
            h = fmaf(qa.z,  w1_s[j * 8 + 2], h);
            h = fmaf(qa.w,  w1_s[j * 8 + 3], h);
            h = fmaf(qbv.x, w1_s[j * 8 + 4], h);
            h = fmaf(qbv.y, w1_s[j * 8 + 5], h);
            h = fmaf(qbv.z, w1_s[j * 8 + 6], h);
            h = fmaf(qbv.w, w1_s[j * 8 + 7], h);
            h = fmaxf(h, 0.0f);
            #pragma unroll
            for (int c2 = 0; c2 < 10; ++c2) ov[c2] = fmaf(h, w2_s[c2 * 32 + j], ov[c2]);
        }
        #pragma unroll
        for (int c2 = 0; c2 < 10; ++c2) {
            ov[c2] += __shfl_xor(ov[c2], 1);
            ov[c2] += __shfl_xor(ov[c2], 2);
            ov[c2] += b2_s[c2];
        }

        const int orow = tile * 16 + srow;
        if (orow < nrows) {
            float2* op = (float2*)(out + (size_t)orow * 10);
            float lo = (s4 == 0) ? ov[0] : (s4 == 1) ? ov[2] : (s4 == 2) ? ov[4] : ov[6];
            float hi = (s4 == 0) ? ov[1] : (s4 == 1) ? ov[3] : (s4 == 2) ? ov[5] : ov[7];
            op[s4] = make_float2(lo, hi);
            if (s4 == 0) op[4] = make_float2(ov[8], ov[9]);
        }
    };

    // tile 0: prefetch crosses into tile 1; tile 1: prefetch re-reads itself (cache hits)
    do_tile(xp0, xp1, tile0);
    do_tile(xp1, xp1, tile0 + 1);
}

extern "C" void kernel_launch(void* const* d_in, const int* in_sizes, int n_in,
                              void* d_out, int out_size, void* d_ws, size_t ws_size,
                              hipStream_t stream) {
    const float* x  = (const float*)d_in[0];
    const float* Wp = (const float*)d_in[1];
    const float* bp = (const float*)d_in[2];
    const float* qw = (const float*)d_in[3];
    const float* W1 = (const float*)d_in[4];
    const float* b1 = (const float*)d_in[5];
    const float* W2 = (const float*)d_in[6];
    const float* b2 = (const float*)d_in[7];
    float* out = (float*)d_out;

    const int nrows = in_sizes[0] / 256;
    const int rows_per_block = 16 * TILES * 4;   // 128
    const int nblocks = (nrows + rows_per_block - 1) / rows_per_block;
    sqru_fused_kernel<<<nblocks, TB, 0, stream>>>(x, Wp, bp, qw, W1, b1, W2, b2, out, nrows);
}

// Round 9
// 32.434 us; speedup vs baseline: 3.1169x; 1.0041x over previous
//
#include <hip/hip_runtime.h>
#include <hip/hip_bf16.h>
#include <math.h>

#define TB 256
#define TILES 2
#define PI_F 3.14159265358979323846f

typedef __attribute__((ext_vector_type(8))) short short8;
typedef __attribute__((ext_vector_type(4))) float f32x4;

union Frag { short8 v; ushort u[8]; uint w[4]; };

__device__ __forceinline__ uint pk2(float a, float b) {
    union { __hip_bfloat162 h; uint u; } cv;
    cv.h = __float22bfloat162_rn(make_float2(a, b));   // packed RNE cvt
    return cv.u;
}

// x path: hi-only bf16 (4 packed cvts per 8 floats)
__device__ __forceinline__ void cvt_hi(const float4& p0, const float4& p1, Frag& hi) {
    hi.w[0] = pk2(p0.x, p0.y); hi.w[1] = pk2(p0.z, p0.w);
    hi.w[2] = pk2(p1.x, p1.y); hi.w[3] = pk2(p1.z, p1.w);
}

// Wp path (one-time): hi + residual lo
__device__ __forceinline__ void cvt8(const float4& p0, const float4& p1, Frag& hi, Frag& lo) {
    float f[8] = {p0.x, p0.y, p0.z, p0.w, p1.x, p1.y, p1.z, p1.w};
    #pragma unroll
    for (int e = 0; e < 4; ++e) hi.w[e] = pk2(f[2 * e], f[2 * e + 1]);
    #pragma unroll
    for (int e = 0; e < 4; ++e) {
        float r0 = f[2 * e]     - __uint_as_float(hi.w[e] << 16);
        float r1 = f[2 * e + 1] - __uint_as_float(hi.w[e] & 0xffff0000u);
        lo.w[e] = pk2(r0, r1);
    }
}

__device__ __forceinline__ float fast_tanh(float p) {
    float t = __expf(2.0f * p);
    return 1.0f - __fdividef(2.0f, t + 1.0f);
}

__global__ __launch_bounds__(TB, 3) void sqru_fused_kernel(
    const float* __restrict__ x, const float* __restrict__ Wp,
    const float* __restrict__ bp, const float* __restrict__ qw,
    const float* __restrict__ W1, const float* __restrict__ b1,
    const float* __restrict__ W2, const float* __restrict__ b2,
    float* __restrict__ out, int nrows)
{
    __shared__ ushort whi[512 * 8];        // 8 KB Wp hi frags [(s*4+kbi)*16+jc]
    __shared__ ushort wlo[512 * 8];        // 8 KB Wp lo frags
    __shared__ float  proj_s[4][16 * 17];  // wave-private transpose
    __shared__ float  qbuf[4][16][8];
    __shared__ float  w1_s[32 * 8];
    __shared__ float  w2_s[10 * 32];
    __shared__ float  b1_s[32];
    __shared__ float  b2_s[10];
    __shared__ float  rot_s[8][3][6];

    const int t   = threadIdx.x;
    const int w   = t >> 6;
    const int l   = t & 63;
    const int jc  = l & 15;     // M-row (batch row) and N-col (proj out) index
    const int kbi = l >> 4;     // K sub-group
    const int gw  = blockIdx.x * 4 + w;
    const int tile0 = gw * TILES;

    int r0 = tile0 * 16 + jc;       if (r0 >= nrows) r0 = nrows - 1;
    int r1 = (tile0 + 1) * 16 + jc; if (r1 >= nrows) r1 = nrows - 1;
    const float* xp0 = x + (size_t)r0 * 256 + kbi * 8;
    const float* xp1 = x + (size_t)r1 * 256 + kbi * 8;

    // ---- ring prologue: ALL of tile0 (8 K-steps) in flight before staging ----
    float4 xa0 = *(const float4*)(xp0 +   0), xb0 = *(const float4*)(xp0 +   4);
    float4 xa1 = *(const float4*)(xp0 +  32), xb1 = *(const float4*)(xp0 +  36);
    float4 xa2 = *(const float4*)(xp0 +  64), xb2 = *(const float4*)(xp0 +  68);
    float4 xa3 = *(const float4*)(xp0 +  96), xb3 = *(const float4*)(xp0 + 100);
    float4 xa4 = *(const float4*)(xp0 + 128), xb4 = *(const float4*)(xp0 + 132);
    float4 xa5 = *(const float4*)(xp0 + 160), xb5 = *(const float4*)(xp0 + 164);
    float4 xa6 = *(const float4*)(xp0 + 192), xb6 = *(const float4*)(xp0 + 196);
    float4 xa7 = *(const float4*)(xp0 + 224), xb7 = *(const float4*)(xp0 + 228);

    // ---- one-time weight staging ----
    if (t < 64) ((float4*)w1_s)[t] = ((const float4*)W1)[t];
    if (t < 80) ((float4*)w2_s)[t] = ((const float4*)W2)[t];
    if (t < 32) b1_s[t] = b1[t];
    if (t < 10) b2_s[t] = b2[t];
    if (t < 24) {
        int u = t / 3, l2 = t % 3;
        float q0 = qw[u * 9 + l2 * 3 + 0];
        float q1 = qw[u * 9 + l2 * 3 + 1];
        float q2 = qw[u * 9 + l2 * 3 + 2];
        rot_s[u][l2][0] = cosf(q0);        rot_s[u][l2][1] = sinf(q0);
        rot_s[u][l2][2] = cosf(0.5f * q1); rot_s[u][l2][3] = sinf(0.5f * q1);
        rot_s[u][l2][4] = cosf(q2);        rot_s[u][l2][5] = sinf(q2);
    }
    #pragma unroll
    for (int ff = 0; ff < 2; ++ff) {
        int f = t + ff * 256;
        int jc2 = f & 15, kb2 = (f >> 4) & 3, s2 = f >> 6;
        const float* wp = Wp + jc2 * 256 + s2 * 32 + kb2 * 8;
        float4 p0 = *(const float4*)wp;
        float4 p1 = *(const float4*)(wp + 4);
        Frag h, lo2;
        cvt8(p0, p1, h, lo2);
        ((short8*)whi)[f] = h.v;
        ((short8*)wlo)[f] = lo2.v;
    }
    __syncthreads();   // only barrier in the kernel

    const float bpj  = bp[jc];
    const int   srow = l >> 2;
    const int   s4   = l & 3;
    const short8* whi_f = (const short8*)whi;
    const short8* wlo_f = (const short8*)wlo;

    auto do_tile = [&](const float* xpn, int tile, bool refill) {
        f32x4 accm = {bpj, bpj, bpj, bpj};
        f32x4 accc = {0.0f, 0.0f, 0.0f, 0.0f};

        // 8 static K-steps; each consumes its slot, then refills it from next tile
        #define STEP(S, XA, XB)                                                     \
        {                                                                           \
            Frag ah; cvt_hi(XA, XB, ah);                                            \
            if (refill) {                                                           \
                XA = *(const float4*)(xpn + (S) * 32);                              \
                XB = *(const float4*)(xpn + (S) * 32 + 4);                          \
            }                                                                       \
            Frag bh, bl;                                                            \
            bh.v = whi_f[((S) * 4 + kbi) * 16 + jc];                                \
            bl.v = wlo_f[((S) * 4 + kbi) * 16 + jc];                                \
            accm = __builtin_amdgcn_mfma_f32_16x16x32_bf16(ah.v, bh.v, accm, 0, 0, 0); \
            accc = __builtin_amdgcn_mfma_f32_16x16x32_bf16(ah.v, bl.v, accc, 0, 0, 0); \
        }
        STEP(0, xa0, xb0)
        STEP(1, xa1, xb1)
        STEP(2, xa2, xb2)
        STEP(3, xa3, xb3)
        STEP(4, xa4, xb4)
        STEP(5, xa5, xb5)
        STEP(6, xa6, xb6)
        STEP(7, xa7, xb7)
        #undef STEP

        // ---- transpose C[row=kbi*4+r][col=jc] via wave-private LDS ----
        #pragma unroll
        for (int r = 0; r < 4; ++r)
            proj_s[w][(kbi * 4 + r) * 17 + jc] = accm[r] + accc[r];

        float4 pv = *(const float4*)&proj_s[w][srow * 17 + s4 * 4];

        // ---- unit-split circuit: 4 lanes/row, 2 units each ----
        float qv[2];
        #pragma unroll
        for (int uu = 0; uu < 2; ++uu) {
            const int u = 2 * s4 + uu;
            float p0 = (uu == 0) ? pv.x : pv.z;
            float p1 = (uu == 0) ? pv.y : pv.w;
            float th0 = fast_tanh(p0);
            float th1 = fast_tanh(p1);
            float c  = __cosf(0.5f * PI_F * th0);
            float s  = __sinf(0.5f * PI_F * th0);
            float zr = __cosf(PI_F * th1);
            float zi = __sinf(PI_F * th1);

            float ar = c, ai = 0.0f, br = s, bi = 0.0f;
            #pragma unroll
            for (int l2 = 0; l2 < 3; ++l2) {
                if (l2 > 0) {
                    float nar = c * ar - s * br, nai = c * ai - s * bi;
                    float nbr = s * ar + c * br, nbi = s * ai + c * bi;
                    ar = nar; ai = nai; br = nbr; bi = nbi;
                }
                float e0r = rot_s[u][l2][0], e0i = rot_s[u][l2][1];
                float p2r = zr * e0r - zi * e0i;
                float p2q = zr * e0i + zi * e0r;
                float nbr = br * p2r - bi * p2q, nbi = br * p2q + bi * p2r;
                br = nbr; bi = nbi;
                float c1 = rot_s[u][l2][2], s1 = rot_s[u][l2][3];
                float tar = c1 * ar - s1 * br, tai = c1 * ai - s1 * bi;
                float tbr = s1 * ar + c1 * br, tbi = s1 * ai + c1 * bi;
                ar = tar; ai = tai; br = tbr; bi = tbi;
                if (l2 < 2) {
                    float e2r = rot_s[u][l2][4], e2i = rot_s[u][l2][5];
                    float ubr = br * e2r - bi * e2i, ubi = br * e2i + bi * e2r;
                    br = ubr; bi = ubi;
                }
            }
            qv[uu] = (ar * ar + ai * ai) - (br * br + bi * bi);
        }

        float* qb = &qbuf[w][srow][0];
        *(float2*)(qb + 2 * s4) = make_float2(qv[0], qv[1]);
        float4 qa  = *(const float4*)(qb + 0);
        float4 qbv = *(const float4*)(qb + 4);

        // ---- head: lane covers j = s4*8..s4*8+7, 4-lane reduce ----
        float ov[10];
        #pragma unroll
        for (int c2 = 0; c2 < 10; ++c2) ov[c2] = 0.0f;
        #pragma unroll
        for (int jj = 0; jj < 8; ++jj) {
            const int j = s4 * 8 + jj;
            float h = b1_s[j];
            h = fmaf(qa.x,  w1_s[j * 8 + 0], h);
            h = fmaf(qa.y,  w1_s[j * 8 + 1], h);
            h = fmaf(qa.z,  w1_s[j * 8 + 2], h);
            h = fmaf(qa.w,  w1_s[j * 8 + 3], h);
            h = fmaf(qbv.x, w1_s[j * 8 + 4], h);
            h = fmaf(qbv.y, w1_s[j * 8 + 5], h);
            h = fmaf(qbv.z, w1_s[j * 8 + 6], h);
            h = fmaf(qbv.w, w1_s[j * 8 + 7], h);
            h = fmaxf(h, 0.0f);
            #pragma unroll
            for (int c2 = 0; c2 < 10; ++c2) ov[c2] = fmaf(h, w2_s[c2 * 32 + j], ov[c2]);
        }
        #pragma unroll
        for (int c2 = 0; c2 < 10; ++c2) {
            ov[c2] += __shfl_xor(ov[c2], 1);
            ov[c2] += __shfl_xor(ov[c2], 2);
            ov[c2] += b2_s[c2];
        }

        const int orow = tile * 16 + srow;
        if (orow < nrows) {
            float2* op = (float2*)(out + (size_t)orow * 10);
            float lo = (s4 == 0) ? ov[0] : (s4 == 1) ? ov[2] : (s4 == 2) ? ov[4] : ov[6];
            float hi = (s4 == 0) ? ov[1] : (s4 == 1) ? ov[3] : (s4 == 2) ? ov[5] : ov[7];
            op[s4] = make_float2(lo, hi);
            if (s4 == 0) op[4] = make_float2(ov[8], ov[9]);
        }
    };

    do_tile(xp1, tile0, true);        // compute tile0, stream in tile1 behind it
    do_tile(xp1, tile0 + 1, false);   // compute tile1, no refill
}

extern "C" void kernel_launch(void* const* d_in, const int* in_sizes, int n_in,
                              void* d_out, int out_size, void* d_ws, size_t ws_size,
                              hipStream_t stream) {
    const float* x  = (const float*)d_in[0];
    const float* Wp = (const float*)d_in[1];
    const float* bp = (const float*)d_in[2];
    const float* qw = (const float*)d_in[3];
    const float* W1 = (const float*)d_in[4];
    const float* b1 = (const float*)d_in[5];
    const float* W2 = (const float*)d_in[6];
    const float* b2 = (const float*)d_in[7];
    float* out = (float*)d_out;

    const int nrows = in_sizes[0] / 256;
    const int rows_per_block = 16 * TILES * 4;   // 128
    const int nblocks = (nrows + rows_per_block - 1) / rows_per_block;
    sqru_fused_kernel<<<nblocks, TB, 0, stream>>>(x, Wp, bp, qw, W1, b1, W2, b2, out, nrows);
}